// Round 8
// baseline (638.415 us; speedup 1.0000x reference)
//
#include <hip/hip_runtime.h>
#include <math.h>

#define BATCH 16
#define OC_TOT 512
#define HH 128
#define WW 128
#define KK 5
#define NOC 32      // output channels per block
#define ROWS 16     // output rows per block
#define NTHREADS 256
#define HW (HH * WW)

typedef float floatx4 __attribute__((ext_vector_type(4)));

// R5 structure (107us): thread = 1 row, two dense 4-col quads (cols 4j..4j+3
// and 64+4j..64+4j+3) -> every store instruction is 16 lanes x 16B contiguous
// (256B runs); nontemporal stores; taps broadcast from LDS as float4.
// R7 change: __launch_bounds__(256,4) caps VGPR at 128 -> 4 waves/SIMD for
// store-latency hiding (R5's (256,2) allowed the allocator to drift past the
// 128-reg occupancy step).
__global__ __launch_bounds__(NTHREADS, 4)
void groupconv_kernel(const float* __restrict__ x,
                      const float* __restrict__ weight,
                      const float* __restrict__ bias,
                      float* __restrict__ out)
{
    __shared__ float sIn[ROWS + 4][WW + 4];   // 20 x 132 input tile (zero halo)
    __shared__ float sW[NOC][28];             // 25 taps + bias + 2 pad

    const int tid = threadIdx.x;
    const int bid = blockIdx.x;
    // grid = BATCH * (HH/ROWS) * (OC_TOT/NOC) = 16*8*16 = 2048
    const int octile = bid & 15;
    const int htile  = (bid >> 4) & 7;
    const int b      = bid >> 7;
    const int h0     = htile * ROWS;
    const int ocbase = octile * NOC;

    // ---- stage input tile (zero halo) ----
    const float* xb = x + b * HW;
    for (int idx = tid; idx < (ROWS + 4) * (WW + 4); idx += NTHREADS) {
        int ry = idx / (WW + 4);
        int cx = idx - ry * (WW + 4);
        int gy = h0 - 2 + ry;
        int gx = cx - 2;
        float v = 0.0f;
        if (gy >= 0 && gy < HH && gx >= 0 && gx < WW)
            v = xb[gy * WW + gx];
        sIn[ry][cx] = v;
    }

    // ---- rotated taps for this block's 32 ocs (d=1 -> plane 0 exactly) ----
    for (int idx = tid; idx < NOC * 25; idx += NTHREADS) {
        int i   = idx / 25;
        int t25 = idx - i * 25;
        int ky  = t25 / 5;
        int kx  = t25 - ky * 5;
        int oc  = ocbase + i;
        int o   = oc >> 4;
        int r   = oc & 15;
        const float* wp = weight + o * 25;
        float theta = 0.39269908169872414f * (float)r;   // 2*pi/16 * r
        float cth = cosf(theta), sth = sinf(theta);
        float ty = ((float)ky + 0.5f) * (2.0f / (float)KK) - 1.0f;
        float tx = ((float)kx + 0.5f) * (2.0f / (float)KK) - 1.0f;
        float xi =  cth * tx + sth * ty;
        float yi = -sth * tx + cth * ty;
        float px = (xi + 1.0f) * ((float)KK * 0.5f) - 0.5f;
        float py = (yi + 1.0f) * ((float)KK * 0.5f) - 0.5f;
        float fx0 = floorf(px), fy0 = floorf(py);
        int   x0 = (int)fx0,  y0 = (int)fy0;
        float wx = px - fx0,  wy = py - fy0;
        float v00 = (y0 >= 0   && y0 < KK   && x0 >= 0   && x0 < KK  ) ? wp[y0 * KK + x0]         : 0.0f;
        float v01 = (y0 >= 0   && y0 < KK   && x0+1 >= 0 && x0+1 < KK) ? wp[y0 * KK + x0 + 1]     : 0.0f;
        float v10 = (y0+1 >= 0 && y0+1 < KK && x0 >= 0   && x0 < KK  ) ? wp[(y0+1) * KK + x0]     : 0.0f;
        float v11 = (y0+1 >= 0 && y0+1 < KK && x0+1 >= 0 && x0+1 < KK) ? wp[(y0+1) * KK + x0 + 1] : 0.0f;
        sW[i][t25] = v00 * (1.0f - wy) * (1.0f - wx)
                   + v01 * (1.0f - wy) * wx
                   + v10 * wy * (1.0f - wx)
                   + v11 * wy * wx;
    }
    for (int i = tid; i < NOC * 3; i += NTHREADS) {
        int oc = i / 3, slot = 25 + (i - oc * 3);
        sW[oc][slot] = (slot == 25) ? bias[(ocbase + oc) >> 4] : 0.0f;
    }
    __syncthreads();

    // ---- thread = 1 row, cols [4j,4j+3] and [64+4j,64+4j+3] ----
    const int row = tid >> 4;           // 0..15
    const int j4  = (tid & 15) * 4;     // 0,4,...,60
    const int h   = h0 + row;

    // two 5x8 windows in registers (20 ds_read_b128, one-time)
    float winA[5][8], winB[5][8];
#pragma unroll
    for (int r5 = 0; r5 < 5; ++r5) {
        float4 a = *(const float4*)&sIn[row + r5][j4];
        float4 c = *(const float4*)&sIn[row + r5][j4 + 4];
        float4 e = *(const float4*)&sIn[row + r5][64 + j4];
        float4 f = *(const float4*)&sIn[row + r5][64 + j4 + 4];
        winA[r5][0] = a.x; winA[r5][1] = a.y; winA[r5][2] = a.z; winA[r5][3] = a.w;
        winA[r5][4] = c.x; winA[r5][5] = c.y; winA[r5][6] = c.z; winA[r5][7] = c.w;
        winB[r5][0] = e.x; winB[r5][1] = e.y; winB[r5][2] = e.z; winB[r5][3] = e.w;
        winB[r5][4] = f.x; winB[r5][5] = f.y; winB[r5][6] = f.z; winB[r5][7] = f.w;
    }

    float* op = out + ((size_t)b * OC_TOT + ocbase) * (size_t)HW
                    + (size_t)h * WW + j4;

#define APPLY(W, KY, KX)                                    \
    a0 = fmaf(winA[KY][(KX)],     (W), a0);                 \
    a1 = fmaf(winA[KY][(KX) + 1], (W), a1);                 \
    a2 = fmaf(winA[KY][(KX) + 2], (W), a2);                 \
    a3 = fmaf(winA[KY][(KX) + 3], (W), a3);                 \
    b0 = fmaf(winB[KY][(KX)],     (W), b0);                 \
    b1 = fmaf(winB[KY][(KX) + 1], (W), b1);                 \
    b2 = fmaf(winB[KY][(KX) + 2], (W), b2);                 \
    b3 = fmaf(winB[KY][(KX) + 3], (W), b3);

    for (int i = 0; i < NOC; ++i) {
        const float4* wrow = (const float4*)&sW[i][0];
        float4 q = wrow[6];                  // {tap24, bias, 0, 0}
        float w44 = q.x;
        float bz  = q.y;
        float a0 = bz, a1 = bz, a2 = bz, a3 = bz;
        float b0 = bz, b1 = bz, b2 = bz, b3 = bz;
        q = wrow[0];  APPLY(q.x,0,0) APPLY(q.y,0,1) APPLY(q.z,0,2) APPLY(q.w,0,3)
        q = wrow[1];  APPLY(q.x,0,4) APPLY(q.y,1,0) APPLY(q.z,1,1) APPLY(q.w,1,2)
        q = wrow[2];  APPLY(q.x,1,3) APPLY(q.y,1,4) APPLY(q.z,2,0) APPLY(q.w,2,1)
        q = wrow[3];  APPLY(q.x,2,2) APPLY(q.y,2,3) APPLY(q.z,2,4) APPLY(q.w,3,0)
        q = wrow[4];  APPLY(q.x,3,1) APPLY(q.y,3,2) APPLY(q.z,3,3) APPLY(q.w,3,4)
        q = wrow[5];  APPLY(q.x,4,0) APPLY(q.y,4,1) APPLY(q.z,4,2) APPLY(q.w,4,3)
        APPLY(w44,4,4)

        floatx4 va = {a0, a1, a2, a3};
        floatx4 vb = {b0, b1, b2, b3};
        __builtin_nontemporal_store(va, (floatx4*)op);
        __builtin_nontemporal_store(vb, (floatx4*)(op + 64));
        op += HW;
    }
#undef APPLY
}

extern "C" void kernel_launch(void* const* d_in, const int* in_sizes, int n_in,
                              void* d_out, int out_size, void* d_ws, size_t ws_size,
                              hipStream_t stream)
{
    const float* x      = (const float*)d_in[0];  // (16,1,128,128)
    const float* weight = (const float*)d_in[1];  // (32,1,1,5,5)
    const float* bias   = (const float*)d_in[2];  // (32,)
    float* out = (float*)d_out;                   // (16,32,16,128,128)

    const int nblocks = BATCH * (HH / ROWS) * (OC_TOT / NOC);  // 2048
    groupconv_kernel<<<nblocks, NTHREADS, 0, stream>>>(x, weight, bias, out);
}

// Round 9
// 186.755 us; speedup vs baseline: 3.4185x; 3.4185x over previous
//
#include <hip/hip_runtime.h>
#include <math.h>

#define BATCH 16
#define OC_TOT 512
#define HH 128
#define WW 128
#define KK 5
#define NOC 32      // output channels per block
#define ROWS 16     // output rows per block
#define NTHREADS 256
#define HW (HH * WW)

typedef float floatx4 __attribute__((ext_vector_type(4)));

// R5 structure (107us): thread = 1 row, two dense 4-col quads (cols 4j..4j+3
// and 64+4j..64+4j+3) -> every store instruction is 16 lanes x 16B contiguous
// (256B runs; each wave covers a contiguous 2KB region); nontemporal stores;
// taps broadcast from LDS as float4.
// R8 change: __launch_bounds__(256,3) -> VGPR cap 168 (vs 256 at (,2)).
// Natural live set ~110-140 regs, so no spill expected; guarantees 3
// waves/SIMD for store-latency hiding. ((,4)=cap 128 proved fatal in R7.)
__global__ __launch_bounds__(NTHREADS, 3)
void groupconv_kernel(const float* __restrict__ x,
                      const float* __restrict__ weight,
                      const float* __restrict__ bias,
                      float* __restrict__ out)
{
    __shared__ float sIn[ROWS + 4][WW + 4];   // 20 x 132 input tile (zero halo)
    __shared__ float sW[NOC][28];             // 25 taps + bias + 2 pad

    const int tid = threadIdx.x;
    const int bid = blockIdx.x;
    // grid = BATCH * (HH/ROWS) * (OC_TOT/NOC) = 16*8*16 = 2048
    const int octile = bid & 15;
    const int htile  = (bid >> 4) & 7;
    const int b      = bid >> 7;
    const int h0     = htile * ROWS;
    const int ocbase = octile * NOC;

    // ---- stage input tile (zero halo) ----
    const float* xb = x + b * HW;
    for (int idx = tid; idx < (ROWS + 4) * (WW + 4); idx += NTHREADS) {
        int ry = idx / (WW + 4);
        int cx = idx - ry * (WW + 4);
        int gy = h0 - 2 + ry;
        int gx = cx - 2;
        float v = 0.0f;
        if (gy >= 0 && gy < HH && gx >= 0 && gx < WW)
            v = xb[gy * WW + gx];
        sIn[ry][cx] = v;
    }

    // ---- rotated taps for this block's 32 ocs (d=1 -> plane 0 exactly) ----
    for (int idx = tid; idx < NOC * 25; idx += NTHREADS) {
        int i   = idx / 25;
        int t25 = idx - i * 25;
        int ky  = t25 / 5;
        int kx  = t25 - ky * 5;
        int oc  = ocbase + i;
        int o   = oc >> 4;
        int r   = oc & 15;
        const float* wp = weight + o * 25;
        float theta = 0.39269908169872414f * (float)r;   // 2*pi/16 * r
        float cth = cosf(theta), sth = sinf(theta);
        float ty = ((float)ky + 0.5f) * (2.0f / (float)KK) - 1.0f;
        float tx = ((float)kx + 0.5f) * (2.0f / (float)KK) - 1.0f;
        float xi =  cth * tx + sth * ty;
        float yi = -sth * tx + cth * ty;
        float px = (xi + 1.0f) * ((float)KK * 0.5f) - 0.5f;
        float py = (yi + 1.0f) * ((float)KK * 0.5f) - 0.5f;
        float fx0 = floorf(px), fy0 = floorf(py);
        int   x0 = (int)fx0,  y0 = (int)fy0;
        float wx = px - fx0,  wy = py - fy0;
        float v00 = (y0 >= 0   && y0 < KK   && x0 >= 0   && x0 < KK  ) ? wp[y0 * KK + x0]         : 0.0f;
        float v01 = (y0 >= 0   && y0 < KK   && x0+1 >= 0 && x0+1 < KK) ? wp[y0 * KK + x0 + 1]     : 0.0f;
        float v10 = (y0+1 >= 0 && y0+1 < KK && x0 >= 0   && x0 < KK  ) ? wp[(y0+1) * KK + x0]     : 0.0f;
        float v11 = (y0+1 >= 0 && y0+1 < KK && x0+1 >= 0 && x0+1 < KK) ? wp[(y0+1) * KK + x0 + 1] : 0.0f;
        sW[i][t25] = v00 * (1.0f - wy) * (1.0f - wx)
                   + v01 * (1.0f - wy) * wx
                   + v10 * wy * (1.0f - wx)
                   + v11 * wy * wx;
    }
    for (int i = tid; i < NOC * 3; i += NTHREADS) {
        int oc = i / 3, slot = 25 + (i - oc * 3);
        sW[oc][slot] = (slot == 25) ? bias[(ocbase + oc) >> 4] : 0.0f;
    }
    __syncthreads();

    // ---- thread = 1 row, cols [4j,4j+3] and [64+4j,64+4j+3] ----
    const int row = tid >> 4;           // 0..15
    const int j4  = (tid & 15) * 4;     // 0,4,...,60
    const int h   = h0 + row;

    // two 5x8 windows in registers (20 ds_read_b128, one-time)
    float winA[5][8], winB[5][8];
#pragma unroll
    for (int r5 = 0; r5 < 5; ++r5) {
        float4 a = *(const float4*)&sIn[row + r5][j4];
        float4 c = *(const float4*)&sIn[row + r5][j4 + 4];
        float4 e = *(const float4*)&sIn[row + r5][64 + j4];
        float4 f = *(const float4*)&sIn[row + r5][64 + j4 + 4];
        winA[r5][0] = a.x; winA[r5][1] = a.y; winA[r5][2] = a.z; winA[r5][3] = a.w;
        winA[r5][4] = c.x; winA[r5][5] = c.y; winA[r5][6] = c.z; winA[r5][7] = c.w;
        winB[r5][0] = e.x; winB[r5][1] = e.y; winB[r5][2] = e.z; winB[r5][3] = e.w;
        winB[r5][4] = f.x; winB[r5][5] = f.y; winB[r5][6] = f.z; winB[r5][7] = f.w;
    }

    float* op = out + ((size_t)b * OC_TOT + ocbase) * (size_t)HW
                    + (size_t)h * WW + j4;

#define APPLY(W, KY, KX)                                    \
    a0 = fmaf(winA[KY][(KX)],     (W), a0);                 \
    a1 = fmaf(winA[KY][(KX) + 1], (W), a1);                 \
    a2 = fmaf(winA[KY][(KX) + 2], (W), a2);                 \
    a3 = fmaf(winA[KY][(KX) + 3], (W), a3);                 \
    b0 = fmaf(winB[KY][(KX)],     (W), b0);                 \
    b1 = fmaf(winB[KY][(KX) + 1], (W), b1);                 \
    b2 = fmaf(winB[KY][(KX) + 2], (W), b2);                 \
    b3 = fmaf(winB[KY][(KX) + 3], (W), b3);

    for (int i = 0; i < NOC; ++i) {
        const float4* wrow = (const float4*)&sW[i][0];
        float4 q = wrow[6];                  // {tap24, bias, 0, 0}
        float w44 = q.x;
        float bz  = q.y;
        float a0 = bz, a1 = bz, a2 = bz, a3 = bz;
        float b0 = bz, b1 = bz, b2 = bz, b3 = bz;
        q = wrow[0];  APPLY(q.x,0,0) APPLY(q.y,0,1) APPLY(q.z,0,2) APPLY(q.w,0,3)
        q = wrow[1];  APPLY(q.x,0,4) APPLY(q.y,1,0) APPLY(q.z,1,1) APPLY(q.w,1,2)
        q = wrow[2];  APPLY(q.x,1,3) APPLY(q.y,1,4) APPLY(q.z,2,0) APPLY(q.w,2,1)
        q = wrow[3];  APPLY(q.x,2,2) APPLY(q.y,2,3) APPLY(q.z,2,4) APPLY(q.w,3,0)
        q = wrow[4];  APPLY(q.x,3,1) APPLY(q.y,3,2) APPLY(q.z,3,3) APPLY(q.w,3,4)
        q = wrow[5];  APPLY(q.x,4,0) APPLY(q.y,4,1) APPLY(q.z,4,2) APPLY(q.w,4,3)
        APPLY(w44,4,4)

        floatx4 va = {a0, a1, a2, a3};
        floatx4 vb = {b0, b1, b2, b3};
        __builtin_nontemporal_store(va, (floatx4*)op);
        __builtin_nontemporal_store(vb, (floatx4*)(op + 64));
        op += HW;
    }
#undef APPLY
}

extern "C" void kernel_launch(void* const* d_in, const int* in_sizes, int n_in,
                              void* d_out, int out_size, void* d_ws, size_t ws_size,
                              hipStream_t stream)
{
    const float* x      = (const float*)d_in[0];  // (16,1,128,128)
    const float* weight = (const float*)d_in[1];  // (32,1,1,5,5)
    const float* bias   = (const float*)d_in[2];  // (32,)
    float* out = (float*)d_out;                   // (16,32,16,128,128)

    const int nblocks = BATCH * (HH / ROWS) * (OC_TOT / NOC);  // 2048
    groupconv_kernel<<<nblocks, NTHREADS, 0, stream>>>(x, weight, bias, out);
}

// Round 10
// 102.481 us; speedup vs baseline: 6.2296x; 1.8223x over previous
//
#include <hip/hip_runtime.h>
#include <math.h>

#define BATCH 16
#define OC_TOT 512
#define HH 128
#define WW 128
#define KK 5
#define NOC 32      // output channels per block
#define ROWS 16     // output rows per block
#define NTHREADS 256
#define HW (HH * WW)
#define TAPS 28     // 25 taps + bias + 2 pad per oc

typedef float floatx4 __attribute__((ext_vector_type(4)));

// ---- kernel 1: rotated tap table (512 x 28 floats) -> d_ws ----
// All the register-hungry trig lives here, not in the hot kernel.
__global__ void tap_kernel(const float* __restrict__ weight,
                           const float* __restrict__ bias,
                           float* __restrict__ tw)
{
    int idx = blockIdx.x * NTHREADS + threadIdx.x;
    if (idx >= OC_TOT * TAPS) return;
    int oc = idx / TAPS;
    int t  = idx - oc * TAPS;
    int o  = oc >> 4;
    int r  = oc & 15;
    float val = 0.0f;
    if (t == 25) {
        val = bias[o];
    } else if (t < 25) {
        int ky = t / 5;
        int kx = t - ky * 5;
        const float* wp = weight + o * 25;   // d=1 -> z-interp selects plane 0 exactly
        float theta = 0.39269908169872414f * (float)r;   // 2*pi/16 * r
        float cth = cosf(theta), sth = sinf(theta);
        float ty = ((float)ky + 0.5f) * (2.0f / (float)KK) - 1.0f;
        float tx = ((float)kx + 0.5f) * (2.0f / (float)KK) - 1.0f;
        float xi =  cth * tx + sth * ty;
        float yi = -sth * tx + cth * ty;
        float px = (xi + 1.0f) * ((float)KK * 0.5f) - 0.5f;
        float py = (yi + 1.0f) * ((float)KK * 0.5f) - 0.5f;
        float fx0 = floorf(px), fy0 = floorf(py);
        int   x0 = (int)fx0,  y0 = (int)fy0;
        float wx = px - fx0,  wy = py - fy0;
        float v00 = (y0 >= 0   && y0 < KK   && x0 >= 0   && x0 < KK  ) ? wp[y0 * KK + x0]         : 0.0f;
        float v01 = (y0 >= 0   && y0 < KK   && x0+1 >= 0 && x0+1 < KK) ? wp[y0 * KK + x0 + 1]     : 0.0f;
        float v10 = (y0+1 >= 0 && y0+1 < KK && x0 >= 0   && x0 < KK  ) ? wp[(y0+1) * KK + x0]     : 0.0f;
        float v11 = (y0+1 >= 0 && y0+1 < KK && x0+1 >= 0 && x0+1 < KK) ? wp[(y0+1) * KK + x0 + 1] : 0.0f;
        val = v00 * (1.0f - wy) * (1.0f - wx)
            + v01 * (1.0f - wy) * wx
            + v10 * wy * (1.0f - wx)
            + v11 * wy * wx;
    }
    tw[idx] = val;
}

// ---- kernel 2: conv. R5 structure (107us) minus the trig phase. ----
// Thread: 1 row, two dense 4-col quads (cols 4j..4j+3, 64+4j..64+4j+3);
// stores 16 lanes x 16B contiguous, nontemporal. Taps copied d_ws->LDS once
// (one coalesced float4 per lane), then broadcast-read per oc as in R5.
__global__ __launch_bounds__(NTHREADS)
void groupconv_kernel(const float* __restrict__ x,
                      const float* __restrict__ tw,
                      float* __restrict__ out)
{
    __shared__ float sIn[ROWS + 4][WW + 4];   // 20 x 132 input tile (zero halo)
    __shared__ float sW[NOC][TAPS];           // 32 x 28 taps(+bias)

    const int tid = threadIdx.x;
    const int bid = blockIdx.x;
    // grid = BATCH * (HH/ROWS) * (OC_TOT/NOC) = 16*8*16 = 2048
    const int octile = bid & 15;
    const int htile  = (bid >> 4) & 7;
    const int b      = bid >> 7;
    const int h0     = htile * ROWS;
    const int ocbase = octile * NOC;

    // ---- stage taps: 32*28 floats = 224 float4s, one per lane ----
    if (tid < NOC * TAPS / 4) {
        ((floatx4*)sW)[tid] = ((const floatx4*)(tw + (size_t)ocbase * TAPS))[tid];
    }

    // ---- stage input tile (zero halo) ----
    const float* xb = x + b * HW;
    for (int idx = tid; idx < (ROWS + 4) * (WW + 4); idx += NTHREADS) {
        int ry = idx / (WW + 4);
        int cx = idx - ry * (WW + 4);
        int gy = h0 - 2 + ry;
        int gx = cx - 2;
        float v = 0.0f;
        if (gy >= 0 && gy < HH && gx >= 0 && gx < WW)
            v = xb[gy * WW + gx];
        sIn[ry][cx] = v;
    }
    __syncthreads();

    // ---- thread = 1 row, cols [4j,4j+3] and [64+4j,64+4j+3] ----
    const int row = tid >> 4;           // 0..15
    const int j4  = (tid & 15) * 4;     // 0,4,...,60
    const int h   = h0 + row;

    // two 5x8 windows in registers (20 ds_read_b128, one-time)
    float winA[5][8], winB[5][8];
#pragma unroll
    for (int r5 = 0; r5 < 5; ++r5) {
        float4 a = *(const float4*)&sIn[row + r5][j4];
        float4 c = *(const float4*)&sIn[row + r5][j4 + 4];
        float4 e = *(const float4*)&sIn[row + r5][64 + j4];
        float4 f = *(const float4*)&sIn[row + r5][64 + j4 + 4];
        winA[r5][0] = a.x; winA[r5][1] = a.y; winA[r5][2] = a.z; winA[r5][3] = a.w;
        winA[r5][4] = c.x; winA[r5][5] = c.y; winA[r5][6] = c.z; winA[r5][7] = c.w;
        winB[r5][0] = e.x; winB[r5][1] = e.y; winB[r5][2] = e.z; winB[r5][3] = e.w;
        winB[r5][4] = f.x; winB[r5][5] = f.y; winB[r5][6] = f.z; winB[r5][7] = f.w;
    }

    float* op = out + ((size_t)b * OC_TOT + ocbase) * (size_t)HW
                    + (size_t)h * WW + j4;

#define APPLY(W, KY, KX)                                    \
    a0 = fmaf(winA[KY][(KX)],     (W), a0);                 \
    a1 = fmaf(winA[KY][(KX) + 1], (W), a1);                 \
    a2 = fmaf(winA[KY][(KX) + 2], (W), a2);                 \
    a3 = fmaf(winA[KY][(KX) + 3], (W), a3);                 \
    b0 = fmaf(winB[KY][(KX)],     (W), b0);                 \
    b1 = fmaf(winB[KY][(KX) + 1], (W), b1);                 \
    b2 = fmaf(winB[KY][(KX) + 2], (W), b2);                 \
    b3 = fmaf(winB[KY][(KX) + 3], (W), b3);

    for (int i = 0; i < NOC; ++i) {
        const float4* wrow = (const float4*)&sW[i][0];
        float4 q = wrow[6];                  // {tap24, bias, 0, 0}
        float w44 = q.x;
        float bz  = q.y;
        float a0 = bz, a1 = bz, a2 = bz, a3 = bz;
        float b0 = bz, b1 = bz, b2 = bz, b3 = bz;
        q = wrow[0];  APPLY(q.x,0,0) APPLY(q.y,0,1) APPLY(q.z,0,2) APPLY(q.w,0,3)
        q = wrow[1];  APPLY(q.x,0,4) APPLY(q.y,1,0) APPLY(q.z,1,1) APPLY(q.w,1,2)
        q = wrow[2];  APPLY(q.x,1,3) APPLY(q.y,1,4) APPLY(q.z,2,0) APPLY(q.w,2,1)
        q = wrow[3];  APPLY(q.x,2,2) APPLY(q.y,2,3) APPLY(q.z,2,4) APPLY(q.w,3,0)
        q = wrow[4];  APPLY(q.x,3,1) APPLY(q.y,3,2) APPLY(q.z,3,3) APPLY(q.w,3,4)
        q = wrow[5];  APPLY(q.x,4,0) APPLY(q.y,4,1) APPLY(q.z,4,2) APPLY(q.w,4,3)
        APPLY(w44,4,4)

        floatx4 va = {a0, a1, a2, a3};
        floatx4 vb = {b0, b1, b2, b3};
        __builtin_nontemporal_store(va, (floatx4*)op);
        __builtin_nontemporal_store(vb, (floatx4*)(op + 64));
        op += HW;
    }
#undef APPLY
}

extern "C" void kernel_launch(void* const* d_in, const int* in_sizes, int n_in,
                              void* d_out, int out_size, void* d_ws, size_t ws_size,
                              hipStream_t stream)
{
    const float* x      = (const float*)d_in[0];  // (16,1,128,128)
    const float* weight = (const float*)d_in[1];  // (32,1,1,5,5)
    const float* bias   = (const float*)d_in[2];  // (32,)
    float* out = (float*)d_out;                   // (16,32,16,128,128)
    float* tw  = (float*)d_ws;                    // 512*28 floats = 57344 B

    const int ntap = OC_TOT * TAPS;
    tap_kernel<<<(ntap + NTHREADS - 1) / NTHREADS, NTHREADS, 0, stream>>>(weight, bias, tw);

    const int nblocks = BATCH * (HH / ROWS) * (OC_TOT / NOC);  // 2048
    groupconv_kernel<<<nblocks, NTHREADS, 0, stream>>>(x, tw, out);
}

// Round 11
// 100.933 us; speedup vs baseline: 6.3251x; 1.0153x over previous
//
#include <hip/hip_runtime.h>
#include <math.h>

#define BATCH 16
#define OC_TOT 512
#define HH 128
#define WW 128
#define KK 5
#define NOC 32      // output channels per block
#define ROWS 16     // output rows per block
#define NTHREADS 256
#define HW (HH * WW)
#define TAPS 28     // 25 taps + bias + 2 pad per oc

typedef float floatx4 __attribute__((ext_vector_type(4)));

// ---- kernel 1: rotated tap table (512 x 28 floats) -> d_ws ----
__global__ void tap_kernel(const float* __restrict__ weight,
                           const float* __restrict__ bias,
                           float* __restrict__ tw)
{
    int idx = blockIdx.x * NTHREADS + threadIdx.x;
    if (idx >= OC_TOT * TAPS) return;
    int oc = idx / TAPS;
    int t  = idx - oc * TAPS;
    int o  = oc >> 4;
    int r  = oc & 15;
    float val = 0.0f;
    if (t == 25) {
        val = bias[o];
    } else if (t < 25) {
        int ky = t / 5;
        int kx = t - ky * 5;
        const float* wp = weight + o * 25;   // d=1 -> z-interp selects plane 0 exactly
        float theta = 0.39269908169872414f * (float)r;   // 2*pi/16 * r
        float cth = cosf(theta), sth = sinf(theta);
        float ty = ((float)ky + 0.5f) * (2.0f / (float)KK) - 1.0f;
        float tx = ((float)kx + 0.5f) * (2.0f / (float)KK) - 1.0f;
        float xi =  cth * tx + sth * ty;
        float yi = -sth * tx + cth * ty;
        float px = (xi + 1.0f) * ((float)KK * 0.5f) - 0.5f;
        float py = (yi + 1.0f) * ((float)KK * 0.5f) - 0.5f;
        float fx0 = floorf(px), fy0 = floorf(py);
        int   x0 = (int)fx0,  y0 = (int)fy0;
        float wx = px - fx0,  wy = py - fy0;
        float v00 = (y0 >= 0   && y0 < KK   && x0 >= 0   && x0 < KK  ) ? wp[y0 * KK + x0]         : 0.0f;
        float v01 = (y0 >= 0   && y0 < KK   && x0+1 >= 0 && x0+1 < KK) ? wp[y0 * KK + x0 + 1]     : 0.0f;
        float v10 = (y0+1 >= 0 && y0+1 < KK && x0 >= 0   && x0 < KK  ) ? wp[(y0+1) * KK + x0]     : 0.0f;
        float v11 = (y0+1 >= 0 && y0+1 < KK && x0+1 >= 0 && x0+1 < KK) ? wp[(y0+1) * KK + x0 + 1] : 0.0f;
        val = v00 * (1.0f - wy) * (1.0f - wx)
            + v01 * (1.0f - wy) * wx
            + v10 * wy * (1.0f - wx)
            + v11 * wy * wx;
    }
    tw[idx] = val;
}

// ---- kernel 2: conv ----
// Thread: 2 rows x one 4-col quad (cols 4j..4j+3), j = tid&31 -> a wave's 32
// lanes cover a full 128-col row: every store instruction is a 512B dense run.
// Window = win[6][8] (48 regs, vs 80 in the 1-row/2-quad shape) -> higher
// occupancy for store-latency hiding. Taps staged d_ws->LDS once, broadcast
// per oc; nontemporal stores.
__global__ __launch_bounds__(NTHREADS)
void groupconv_kernel(const float* __restrict__ x,
                      const float* __restrict__ tw,
                      float* __restrict__ out)
{
    __shared__ float sIn[ROWS + 4][WW + 4];   // 20 x 132 input tile (zero halo)
    __shared__ float sW[NOC][TAPS];           // 32 x 28 taps(+bias)

    const int tid = threadIdx.x;
    const int bid = blockIdx.x;
    // grid = BATCH * (HH/ROWS) * (OC_TOT/NOC) = 16*8*16 = 2048
    const int octile = bid & 15;
    const int htile  = (bid >> 4) & 7;
    const int b      = bid >> 7;
    const int h0     = htile * ROWS;
    const int ocbase = octile * NOC;

    // ---- stage taps: 32*28 floats = 224 float4s, one per lane ----
    if (tid < NOC * TAPS / 4) {
        ((floatx4*)sW)[tid] = ((const floatx4*)(tw + (size_t)ocbase * TAPS))[tid];
    }

    // ---- stage input tile (zero halo) ----
    const float* xb = x + b * HW;
    for (int idx = tid; idx < (ROWS + 4) * (WW + 4); idx += NTHREADS) {
        int ry = idx / (WW + 4);
        int cx = idx - ry * (WW + 4);
        int gy = h0 - 2 + ry;
        int gx = cx - 2;
        float v = 0.0f;
        if (gy >= 0 && gy < HH && gx >= 0 && gx < WW)
            v = xb[gy * WW + gx];
        sIn[ry][cx] = v;
    }
    __syncthreads();

    // ---- thread = rows {2p, 2p+1}, cols [4j, 4j+3] ----
    const int p   = tid >> 5;           // 0..7 (row pair)
    const int j4  = (tid & 31) * 4;     // 0,4,...,124
    const int y0r = h0 + 2 * p;

    // 6x8 window in registers (12 ds_read_b128, one-time)
    float win[6][8];
#pragma unroll
    for (int r6 = 0; r6 < 6; ++r6) {
        float4 a = *(const float4*)&sIn[2 * p + r6][j4];
        float4 c = *(const float4*)&sIn[2 * p + r6][j4 + 4];
        win[r6][0] = a.x; win[r6][1] = a.y; win[r6][2] = a.z; win[r6][3] = a.w;
        win[r6][4] = c.x; win[r6][5] = c.y; win[r6][6] = c.z; win[r6][7] = c.w;
    }

    float* op = out + ((size_t)b * OC_TOT + ocbase) * (size_t)HW
                    + (size_t)y0r * WW + j4;

#define APPLY(W, KY, KX)                                    \
    a0 = fmaf(win[KY][(KX)],     (W), a0);                  \
    a1 = fmaf(win[KY][(KX) + 1], (W), a1);                  \
    a2 = fmaf(win[KY][(KX) + 2], (W), a2);                  \
    a3 = fmaf(win[KY][(KX) + 3], (W), a3);                  \
    b0 = fmaf(win[KY + 1][(KX)],     (W), b0);              \
    b1 = fmaf(win[KY + 1][(KX) + 1], (W), b1);              \
    b2 = fmaf(win[KY + 1][(KX) + 2], (W), b2);              \
    b3 = fmaf(win[KY + 1][(KX) + 3], (W), b3);

    for (int i = 0; i < NOC; ++i) {
        const float4* wrow = (const float4*)&sW[i][0];
        float4 q = wrow[6];                  // {tap24, bias, 0, 0}
        float w44 = q.x;
        float bz  = q.y;
        float a0 = bz, a1 = bz, a2 = bz, a3 = bz;   // row 2p
        float b0 = bz, b1 = bz, b2 = bz, b3 = bz;   // row 2p+1
        q = wrow[0];  APPLY(q.x,0,0) APPLY(q.y,0,1) APPLY(q.z,0,2) APPLY(q.w,0,3)
        q = wrow[1];  APPLY(q.x,0,4) APPLY(q.y,1,0) APPLY(q.z,1,1) APPLY(q.w,1,2)
        q = wrow[2];  APPLY(q.x,1,3) APPLY(q.y,1,4) APPLY(q.z,2,0) APPLY(q.w,2,1)
        q = wrow[3];  APPLY(q.x,2,2) APPLY(q.y,2,3) APPLY(q.z,2,4) APPLY(q.w,3,0)
        q = wrow[4];  APPLY(q.x,3,1) APPLY(q.y,3,2) APPLY(q.z,3,3) APPLY(q.w,3,4)
        q = wrow[5];  APPLY(q.x,4,0) APPLY(q.y,4,1) APPLY(q.z,4,2) APPLY(q.w,4,3)
        APPLY(w44,4,4)

        floatx4 va = {a0, a1, a2, a3};
        floatx4 vb = {b0, b1, b2, b3};
        __builtin_nontemporal_store(va, (floatx4*)op);
        __builtin_nontemporal_store(vb, (floatx4*)(op + WW));
        op += HW;
    }
#undef APPLY
}

extern "C" void kernel_launch(void* const* d_in, const int* in_sizes, int n_in,
                              void* d_out, int out_size, void* d_ws, size_t ws_size,
                              hipStream_t stream)
{
    const float* x      = (const float*)d_in[0];  // (16,1,128,128)
    const float* weight = (const float*)d_in[1];  // (32,1,1,5,5)
    const float* bias   = (const float*)d_in[2];  // (32,)
    float* out = (float*)d_out;                   // (16,32,16,128,128)
    float* tw  = (float*)d_ws;                    // 512*28 floats = 57344 B

    const int ntap = OC_TOT * TAPS;
    tap_kernel<<<(ntap + NTHREADS - 1) / NTHREADS, NTHREADS, 0, stream>>>(weight, bias, tw);

    const int nblocks = BATCH * (HH / ROWS) * (OC_TOT / NOC);  // 2048
    groupconv_kernel<<<nblocks, NTHREADS, 0, stream>>>(x, tw, out);
}

// Round 12
// 98.986 us; speedup vs baseline: 6.4495x; 1.0197x over previous
//
#include <hip/hip_runtime.h>
#include <math.h>

#define BATCH 16
#define OC_TOT 512
#define HH 128
#define WW 128
#define KK 5
#define NOC 32      // output channels per block
#define BROWS 32    // output rows per block
#define NTHREADS 256
#define HW (HH * WW)
#define TAPS 28     // 25 taps + bias + 2 pad per oc

typedef float floatx4 __attribute__((ext_vector_type(4)));

// ---- kernel 1: rotated tap table (512 x 28 floats) -> d_ws ----
__global__ void tap_kernel(const float* __restrict__ weight,
                           const float* __restrict__ bias,
                           float* __restrict__ tw)
{
    int idx = blockIdx.x * NTHREADS + threadIdx.x;
    if (idx >= OC_TOT * TAPS) return;
    int oc = idx / TAPS;
    int t  = idx - oc * TAPS;
    int o  = oc >> 4;
    int r  = oc & 15;
    float val = 0.0f;
    if (t == 25) {
        val = bias[o];
    } else if (t < 25) {
        int ky = t / 5;
        int kx = t - ky * 5;
        const float* wp = weight + o * 25;   // d=1 -> z-interp selects plane 0 exactly
        float theta = 0.39269908169872414f * (float)r;   // 2*pi/16 * r
        float cth = cosf(theta), sth = sinf(theta);
        float ty = ((float)ky + 0.5f) * (2.0f / (float)KK) - 1.0f;
        float tx = ((float)kx + 0.5f) * (2.0f / (float)KK) - 1.0f;
        float xi =  cth * tx + sth * ty;
        float yi = -sth * tx + cth * ty;
        float px = (xi + 1.0f) * ((float)KK * 0.5f) - 0.5f;
        float py = (yi + 1.0f) * ((float)KK * 0.5f) - 0.5f;
        float fx0 = floorf(px), fy0 = floorf(py);
        int   x0 = (int)fx0,  y0 = (int)fy0;
        float wx = px - fx0,  wy = py - fy0;
        float v00 = (y0 >= 0   && y0 < KK   && x0 >= 0   && x0 < KK  ) ? wp[y0 * KK + x0]         : 0.0f;
        float v01 = (y0 >= 0   && y0 < KK   && x0+1 >= 0 && x0+1 < KK) ? wp[y0 * KK + x0 + 1]     : 0.0f;
        float v10 = (y0+1 >= 0 && y0+1 < KK && x0 >= 0   && x0 < KK  ) ? wp[(y0+1) * KK + x0]     : 0.0f;
        float v11 = (y0+1 >= 0 && y0+1 < KK && x0+1 >= 0 && x0+1 < KK) ? wp[(y0+1) * KK + x0 + 1] : 0.0f;
        val = v00 * (1.0f - wy) * (1.0f - wx)
            + v01 * (1.0f - wy) * wx
            + v10 * wy * (1.0f - wx)
            + v11 * wy * wx;
    }
    tw[idx] = val;
}

// ---- kernel 2: conv ----
// Thread: 4 rows x one 4-col quad (cols 4j..4j+3), j = tid&31 -> wave covers
// a full 128-col row per store instruction (512B dense runs), 4 rows per oc.
// 16 outputs/oc amortize the 7 tap broadcasts 2x vs R10. Window win[8][8] =
// 64 regs (vs 96 in the failed R6 shape), trig outsourced -> expect <=128
// VGPR, 4 waves/SIMD. Nontemporal stores.
__global__ __launch_bounds__(NTHREADS)
void groupconv_kernel(const float* __restrict__ x,
                      const float* __restrict__ tw,
                      float* __restrict__ out)
{
    __shared__ float sIn[BROWS + 4][WW + 4];  // 36 x 132 input tile (zero halo)
    __shared__ float sW[NOC][TAPS];           // 32 x 28 taps(+bias)

    const int tid = threadIdx.x;
    const int bid = blockIdx.x;
    // grid = BATCH * (HH/BROWS) * (OC_TOT/NOC) = 16*4*16 = 1024
    const int octile = bid & 15;
    const int htile  = (bid >> 4) & 3;
    const int b      = bid >> 6;
    const int h0     = htile * BROWS;
    const int ocbase = octile * NOC;

    // ---- stage taps: 32*28 floats = 224 float4s, one per lane ----
    if (tid < NOC * TAPS / 4) {
        ((floatx4*)sW)[tid] = ((const floatx4*)(tw + (size_t)ocbase * TAPS))[tid];
    }

    // ---- stage input tile (zero halo) ----
    const float* xb = x + b * HW;
    for (int idx = tid; idx < (BROWS + 4) * (WW + 4); idx += NTHREADS) {
        int ry = idx / (WW + 4);
        int cx = idx - ry * (WW + 4);
        int gy = h0 - 2 + ry;
        int gx = cx - 2;
        float v = 0.0f;
        if (gy >= 0 && gy < HH && gx >= 0 && gx < WW)
            v = xb[gy * WW + gx];
        sIn[ry][cx] = v;
    }
    __syncthreads();

    // ---- thread = rows {4g..4g+3}, cols [4j, 4j+3] ----
    const int g   = tid >> 5;           // 0..7 (row group)
    const int j4  = (tid & 31) * 4;     // 0,4,...,124
    const int y0r = h0 + 4 * g;

    // 8x8 window in registers (16 ds_read_b128, one-time)
    float win[8][8];
#pragma unroll
    for (int r8 = 0; r8 < 8; ++r8) {
        float4 a = *(const float4*)&sIn[4 * g + r8][j4];
        float4 c = *(const float4*)&sIn[4 * g + r8][j4 + 4];
        win[r8][0] = a.x; win[r8][1] = a.y; win[r8][2] = a.z; win[r8][3] = a.w;
        win[r8][4] = c.x; win[r8][5] = c.y; win[r8][6] = c.z; win[r8][7] = c.w;
    }

    float* op = out + ((size_t)b * OC_TOT + ocbase) * (size_t)HW
                    + (size_t)y0r * WW + j4;

#define APPLY(W, KY, KX)                                    \
    a0 = fmaf(win[KY][(KX)],     (W), a0);                  \
    a1 = fmaf(win[KY][(KX) + 1], (W), a1);                  \
    a2 = fmaf(win[KY][(KX) + 2], (W), a2);                  \
    a3 = fmaf(win[KY][(KX) + 3], (W), a3);                  \
    b0 = fmaf(win[KY + 1][(KX)],     (W), b0);              \
    b1 = fmaf(win[KY + 1][(KX) + 1], (W), b1);              \
    b2 = fmaf(win[KY + 1][(KX) + 2], (W), b2);              \
    b3 = fmaf(win[KY + 1][(KX) + 3], (W), b3);              \
    c0 = fmaf(win[KY + 2][(KX)],     (W), c0);              \
    c1 = fmaf(win[KY + 2][(KX) + 1], (W), c1);              \
    c2 = fmaf(win[KY + 2][(KX) + 2], (W), c2);              \
    c3 = fmaf(win[KY + 2][(KX) + 3], (W), c3);              \
    d0 = fmaf(win[KY + 3][(KX)],     (W), d0);              \
    d1 = fmaf(win[KY + 3][(KX) + 1], (W), d1);              \
    d2 = fmaf(win[KY + 3][(KX) + 2], (W), d2);              \
    d3 = fmaf(win[KY + 3][(KX) + 3], (W), d3);

    for (int i = 0; i < NOC; ++i) {
        const float4* wrow = (const float4*)&sW[i][0];
        float4 q = wrow[6];                  // {tap24, bias, 0, 0}
        float w44 = q.x;
        float bz  = q.y;
        float a0 = bz, a1 = bz, a2 = bz, a3 = bz;   // row 4g
        float b0 = bz, b1 = bz, b2 = bz, b3 = bz;   // row 4g+1
        float c0 = bz, c1 = bz, c2 = bz, c3 = bz;   // row 4g+2
        float d0 = bz, d1 = bz, d2 = bz, d3 = bz;   // row 4g+3
        q = wrow[0];  APPLY(q.x,0,0) APPLY(q.y,0,1) APPLY(q.z,0,2) APPLY(q.w,0,3)
        q = wrow[1];  APPLY(q.x,0,4) APPLY(q.y,1,0) APPLY(q.z,1,1) APPLY(q.w,1,2)
        q = wrow[2];  APPLY(q.x,1,3) APPLY(q.y,1,4) APPLY(q.z,2,0) APPLY(q.w,2,1)
        q = wrow[3];  APPLY(q.x,2,2) APPLY(q.y,2,3) APPLY(q.z,2,4) APPLY(q.w,3,0)
        q = wrow[4];  APPLY(q.x,3,1) APPLY(q.y,3,2) APPLY(q.z,3,3) APPLY(q.w,3,4)
        q = wrow[5];  APPLY(q.x,4,0) APPLY(q.y,4,1) APPLY(q.z,4,2) APPLY(q.w,4,3)
        APPLY(w44,4,4)

        floatx4 va = {a0, a1, a2, a3};
        floatx4 vb = {b0, b1, b2, b3};
        floatx4 vc = {c0, c1, c2, c3};
        floatx4 vd = {d0, d1, d2, d3};
        __builtin_nontemporal_store(va, (floatx4*)op);
        __builtin_nontemporal_store(vb, (floatx4*)(op + WW));
        __builtin_nontemporal_store(vc, (floatx4*)(op + 2 * WW));
        __builtin_nontemporal_store(vd, (floatx4*)(op + 3 * WW));
        op += HW;
    }
#undef APPLY
}

extern "C" void kernel_launch(void* const* d_in, const int* in_sizes, int n_in,
                              void* d_out, int out_size, void* d_ws, size_t ws_size,
                              hipStream_t stream)
{
    const float* x      = (const float*)d_in[0];  // (16,1,128,128)
    const float* weight = (const float*)d_in[1];  // (32,1,1,5,5)
    const float* bias   = (const float*)d_in[2];  // (32,)
    float* out = (float*)d_out;                   // (16,32,16,128,128)
    float* tw  = (float*)d_ws;                    // 512*28 floats = 57344 B

    const int ntap = OC_TOT * TAPS;
    tap_kernel<<<(ntap + NTHREADS - 1) / NTHREADS, NTHREADS, 0, stream>>>(weight, bias, tw);

    const int nblocks = BATCH * (HH / BROWS) * (OC_TOT / NOC);  // 1024
    groupconv_kernel<<<nblocks, NTHREADS, 0, stream>>>(x, tw, out);
}

// Round 13
// 98.805 us; speedup vs baseline: 6.4614x; 1.0018x over previous
//
#include <hip/hip_runtime.h>
#include <math.h>

#define BATCH 16
#define OC_TOT 512
#define HH 128
#define WW 128
#define KK 5
#define NOC 32      // output channels per block
#define BROWS 32    // output rows per block
#define NTHREADS 256
#define HW (HH * WW)

typedef float floatx4 __attribute__((ext_vector_type(4)));

// cos/sin(2*pi*r/16) as fp32 literals (trig removed from device code entirely)
__device__ const float CTAB[16] = {
     1.0f,  0.92387953251128674f,  0.70710678118654757f,  0.38268343236508984f,
     0.0f, -0.38268343236508984f, -0.70710678118654757f, -0.92387953251128674f,
    -1.0f, -0.92387953251128674f, -0.70710678118654757f, -0.38268343236508984f,
     0.0f,  0.38268343236508984f,  0.70710678118654757f,  0.92387953251128674f};
__device__ const float STAB[16] = {
     0.0f,  0.38268343236508984f,  0.70710678118654757f,  0.92387953251128674f,
     1.0f,  0.92387953251128674f,  0.70710678118654757f,  0.38268343236508984f,
     0.0f, -0.38268343236508984f, -0.70710678118654757f, -0.92387953251128674f,
    -1.0f, -0.92387953251128674f, -0.70710678118654757f, -0.38268343236508984f};

// Single kernel. Thread: 4 rows x one 4-col quad (cols 4j..4j+3, j=tid&31) ->
// wave covers a full 128-col row per store (512B dense runs), nontemporal.
// Taps computed in-block (trig-free: table lookup + bilinear gather of the
// L2-hot 3.2KB weight), overlapped with input staging before the barrier.
__global__ __launch_bounds__(NTHREADS)
void groupconv_kernel(const float* __restrict__ x,
                      const float* __restrict__ weight,
                      const float* __restrict__ bias,
                      float* __restrict__ out)
{
    __shared__ float sIn[BROWS + 4][WW + 4];  // 36 x 132 input tile (zero halo)
    __shared__ float sW[NOC][28];             // 25 taps + bias + 2 pad

    const int tid = threadIdx.x;
    const int bid = blockIdx.x;
    // grid = BATCH * (HH/BROWS) * (OC_TOT/NOC) = 16*4*16 = 1024
    const int octile = bid & 15;
    const int htile  = (bid >> 4) & 3;
    const int b      = bid >> 6;
    const int h0     = htile * BROWS;
    const int ocbase = octile * NOC;

    // ---- stage input tile (zero halo) ----
    const float* xb = x + b * HW;
    for (int idx = tid; idx < (BROWS + 4) * (WW + 4); idx += NTHREADS) {
        int ry = idx / (WW + 4);
        int cx = idx - ry * (WW + 4);
        int gy = h0 - 2 + ry;
        int gx = cx - 2;
        float v = 0.0f;
        if (gy >= 0 && gy < HH && gx >= 0 && gx < WW)
            v = xb[gy * WW + gx];
        sIn[ry][cx] = v;
    }

    // ---- rotated taps (trig-free; d=1 -> z-interp selects plane 0 exactly) ----
    for (int idx = tid; idx < NOC * 25; idx += NTHREADS) {
        int i   = idx / 25;
        int t25 = idx - i * 25;
        int ky  = t25 / 5;
        int kx  = t25 - ky * 5;
        int oc  = ocbase + i;
        int o   = oc >> 4;
        int r   = oc & 15;
        const float* wp = weight + o * 25;
        float cth = CTAB[r], sth = STAB[r];
        float ty = ((float)ky + 0.5f) * (2.0f / (float)KK) - 1.0f;
        float tx = ((float)kx + 0.5f) * (2.0f / (float)KK) - 1.0f;
        float xi =  cth * tx + sth * ty;
        float yi = -sth * tx + cth * ty;
        float px = (xi + 1.0f) * ((float)KK * 0.5f) - 0.5f;
        float py = (yi + 1.0f) * ((float)KK * 0.5f) - 0.5f;
        float fx0 = floorf(px), fy0 = floorf(py);
        int   x0 = (int)fx0,  y0 = (int)fy0;
        float wx = px - fx0,  wy = py - fy0;
        float v00 = (y0 >= 0   && y0 < KK   && x0 >= 0   && x0 < KK  ) ? wp[y0 * KK + x0]         : 0.0f;
        float v01 = (y0 >= 0   && y0 < KK   && x0+1 >= 0 && x0+1 < KK) ? wp[y0 * KK + x0 + 1]     : 0.0f;
        float v10 = (y0+1 >= 0 && y0+1 < KK && x0 >= 0   && x0 < KK  ) ? wp[(y0+1) * KK + x0]     : 0.0f;
        float v11 = (y0+1 >= 0 && y0+1 < KK && x0+1 >= 0 && x0+1 < KK) ? wp[(y0+1) * KK + x0 + 1] : 0.0f;
        sW[i][t25] = v00 * (1.0f - wy) * (1.0f - wx)
                   + v01 * (1.0f - wy) * wx
                   + v10 * wy * (1.0f - wx)
                   + v11 * wy * wx;
    }
    for (int i = tid; i < NOC * 3; i += NTHREADS) {
        int oc = i / 3, slot = 25 + (i - oc * 3);
        sW[oc][slot] = (slot == 25) ? bias[(ocbase + oc) >> 4] : 0.0f;
    }
    __syncthreads();

    // ---- thread = rows {4g..4g+3}, cols [4j, 4j+3] ----
    const int g   = tid >> 5;           // 0..7 (row group)
    const int j4  = (tid & 31) * 4;     // 0,4,...,124
    const int y0r = h0 + 4 * g;

    // 8x8 window in registers (16 ds_read_b128, one-time)
    float win[8][8];
#pragma unroll
    for (int r8 = 0; r8 < 8; ++r8) {
        float4 a = *(const float4*)&sIn[4 * g + r8][j4];
        float4 c = *(const float4*)&sIn[4 * g + r8][j4 + 4];
        win[r8][0] = a.x; win[r8][1] = a.y; win[r8][2] = a.z; win[r8][3] = a.w;
        win[r8][4] = c.x; win[r8][5] = c.y; win[r8][6] = c.z; win[r8][7] = c.w;
    }

    float* op = out + ((size_t)b * OC_TOT + ocbase) * (size_t)HW
                    + (size_t)y0r * WW + j4;

#define APPLY(W, KY, KX)                                    \
    a0 = fmaf(win[KY][(KX)],     (W), a0);                  \
    a1 = fmaf(win[KY][(KX) + 1], (W), a1);                  \
    a2 = fmaf(win[KY][(KX) + 2], (W), a2);                  \
    a3 = fmaf(win[KY][(KX) + 3], (W), a3);                  \
    b0 = fmaf(win[KY + 1][(KX)],     (W), b0);              \
    b1 = fmaf(win[KY + 1][(KX) + 1], (W), b1);              \
    b2 = fmaf(win[KY + 1][(KX) + 2], (W), b2);              \
    b3 = fmaf(win[KY + 1][(KX) + 3], (W), b3);              \
    c0 = fmaf(win[KY + 2][(KX)],     (W), c0);              \
    c1 = fmaf(win[KY + 2][(KX) + 1], (W), c1);              \
    c2 = fmaf(win[KY + 2][(KX) + 2], (W), c2);              \
    c3 = fmaf(win[KY + 2][(KX) + 3], (W), c3);              \
    d0 = fmaf(win[KY + 3][(KX)],     (W), d0);              \
    d1 = fmaf(win[KY + 3][(KX) + 1], (W), d1);              \
    d2 = fmaf(win[KY + 3][(KX) + 2], (W), d2);              \
    d3 = fmaf(win[KY + 3][(KX) + 3], (W), d3);

    for (int i = 0; i < NOC; ++i) {
        const float4* wrow = (const float4*)&sW[i][0];
        float4 q = wrow[6];                  // {tap24, bias, 0, 0}
        float w44 = q.x;
        float bz  = q.y;
        float a0 = bz, a1 = bz, a2 = bz, a3 = bz;   // row 4g
        float b0 = bz, b1 = bz, b2 = bz, b3 = bz;   // row 4g+1
        float c0 = bz, c1 = bz, c2 = bz, c3 = bz;   // row 4g+2
        float d0 = bz, d1 = bz, d2 = bz, d3 = bz;   // row 4g+3
        q = wrow[0];  APPLY(q.x,0,0) APPLY(q.y,0,1) APPLY(q.z,0,2) APPLY(q.w,0,3)
        q = wrow[1];  APPLY(q.x,0,4) APPLY(q.y,1,0) APPLY(q.z,1,1) APPLY(q.w,1,2)
        q = wrow[2];  APPLY(q.x,1,3) APPLY(q.y,1,4) APPLY(q.z,2,0) APPLY(q.w,2,1)
        q = wrow[3];  APPLY(q.x,2,2) APPLY(q.y,2,3) APPLY(q.z,2,4) APPLY(q.w,3,0)
        q = wrow[4];  APPLY(q.x,3,1) APPLY(q.y,3,2) APPLY(q.z,3,3) APPLY(q.w,3,4)
        q = wrow[5];  APPLY(q.x,4,0) APPLY(q.y,4,1) APPLY(q.z,4,2) APPLY(q.w,4,3)
        APPLY(w44,4,4)

        floatx4 va = {a0, a1, a2, a3};
        floatx4 vb = {b0, b1, b2, b3};
        floatx4 vc = {c0, c1, c2, c3};
        floatx4 vd = {d0, d1, d2, d3};
        __builtin_nontemporal_store(va, (floatx4*)op);
        __builtin_nontemporal_store(vb, (floatx4*)(op + WW));
        __builtin_nontemporal_store(vc, (floatx4*)(op + 2 * WW));
        __builtin_nontemporal_store(vd, (floatx4*)(op + 3 * WW));
        op += HW;
    }
#undef APPLY
}

extern "C" void kernel_launch(void* const* d_in, const int* in_sizes, int n_in,
                              void* d_out, int out_size, void* d_ws, size_t ws_size,
                              hipStream_t stream)
{
    const float* x      = (const float*)d_in[0];  // (16,1,128,128)
    const float* weight = (const float*)d_in[1];  // (32,1,1,5,5)
    const float* bias   = (const float*)d_in[2];  // (32,)
    float* out = (float*)d_out;                   // (16,32,16,128,128)

    const int nblocks = BATCH * (HH / BROWS) * (OC_TOT / NOC);  // 1024
    groupconv_kernel<<<nblocks, NTHREADS, 0, stream>>>(x, weight, bias, out);
}